// Round 4
// baseline (729.914 us; speedup 1.0000x reference)
//
#include <hip/hip_runtime.h>
#include <hip/hip_bf16.h>
#include <stdint.h>

typedef __bf16 bf16_t;
typedef __attribute__((ext_vector_type(8))) __bf16 bf16x8;

__device__ __forceinline__ float cvt(float v)  { return v; }
__device__ __forceinline__ float cvt(bf16_t v) { return (float)v; }

// load 8 consecutive values (16B-aligned for bf16, 32B for f32) as fp32
template<typename PT>
__device__ __forceinline__ void load8f(const PT* p, float o[8]) {
    if constexpr (sizeof(PT) == 4) {
        const float4* q = (const float4*)p;
        float4 a = q[0], b = q[1];
        o[0]=a.x; o[1]=a.y; o[2]=a.z; o[3]=a.w;
        o[4]=b.x; o[5]=b.y; o[6]=b.z; o[7]=b.w;
    } else {
        bf16x8 v = *(const bf16x8*)p;
        #pragma unroll
        for (int i = 0; i < 8; ++i) o[i] = (float)v[i];
    }
}

// A&S 7.1.26 erf approximation, |abs err| <= 1.5e-7
__device__ __forceinline__ float erf_approx(float x) {
    float ax = fabsf(x);
    float t  = __builtin_amdgcn_rcpf(1.0f + 0.3275911f * ax);
    float y  = t * (0.254829592f + t * (-0.284496736f + t * (1.421413741f +
               t * (-1.453152027f + t * 1.061405429f))));
    float r  = 1.0f - y * __expf(-ax * ax);
    return copysignf(r, x);
}
__device__ __forceinline__ float gelu_exact(float x) {
    return 0.5f * x * (1.0f + erf_approx(x * 0.70710678118654752f));
}

// ---------------------------------------------------------------------------
// Kernel 0: dtype detection. flag: 1 = fp32, 2 = bf16.
// ---------------------------------------------------------------------------
__global__ void detect_dtype(const uint32_t* __restrict__ bits, int* __restrict__ flag) {
    int l = threadIdx.x;
    int cnt = 0;
    for (int i = l; i < 256; i += 64) {
        float v = __uint_as_float(bits[i]);
        if (v == v && fabsf(v) < 1024.0f) cnt++;
    }
    cnt += __shfl_xor(cnt, 1);  cnt += __shfl_xor(cnt, 2);
    cnt += __shfl_xor(cnt, 4);  cnt += __shfl_xor(cnt, 8);
    cnt += __shfl_xor(cnt, 16); cnt += __shfl_xor(cnt, 32);
    if (l == 0) *flag = (cnt >= 128) ? 1 : 2;
}

// ---------------------------------------------------------------------------
// Kernel 1: DIRECT per-node projection (no MFMA, no async, no transpose tables).
// For node n, col c<128:  P1[n][c]  = sum_k feat[n][k] * W1[koff+k][c]  (+ b1[c] if fold)
//            col c>=128: P2[n][c-128] = sum_k feat[n][k] * Ws[koff+k][c-128] (+ bs if fold)
// 4 nodes/block, 192 threads (one col each), feat rows staged in LDS fp32.
// ---------------------------------------------------------------------------
template<typename T, int DTYPE, typename PT>
__global__ void prep_direct(const int* __restrict__ flag,
                            const T* __restrict__ feat,
                            const T* __restrict__ W1, const T* __restrict__ Wsc,
                            const T* __restrict__ b1, const T* __restrict__ bsv,
                            PT* __restrict__ P1, PT* __restrict__ P2,
                            int koff, int fold, int ND) {
    if (*flag != DTYPE) return;
    __shared__ float shF[4][256];
    const int t = threadIdx.x;
    const int n0 = blockIdx.x * 4;

    for (int u = t; u < 1024; u += 192) {
        int j = u >> 8, k = u & 255;
        int node = min(n0 + j, ND - 1);
        shF[j][k] = cvt(feat[(size_t)node * 256 + k]);
    }
    __syncthreads();

    const int c = t;          // 0..191
    const int cc = c - 128;
    float acc[4] = {0.f, 0.f, 0.f, 0.f};
    for (int k = 0; k < 256; ++k) {
        float w = (c < 128) ? cvt(W1[(size_t)(koff + k) * 128 + c])
                            : cvt(Wsc[(size_t)(koff + k) * 64 + cc]);
        #pragma unroll
        for (int j = 0; j < 4; ++j) acc[j] += shF[j][k] * w;
    }
    float bias = 0.f;
    if (fold) bias = (c < 128) ? cvt(b1[c]) : cvt(bsv[cc]);
    #pragma unroll
    for (int j = 0; j < 4; ++j) {
        int node = n0 + j;
        if (node < ND) {
            float v = acc[j] + bias;
            if (c < 128) P1[(size_t)node * 128 + c] = (PT)v;
            else         P2[(size_t)node * 64 + cc] = (PT)v;
        }
    }
}

// ---------------------------------------------------------------------------
// Kernel 2: DIRECT fused edge kernel. 64 edges/block, 256 threads.
// thread t -> edge e=t>>2, quarter q=t&3. t2 via per-thread VALU dots
// (thread t handles edge t>>2, channels (t&3)*16..+15). No MFMA, no overlay
// tricks: shT reuses shH storage only after all shH reads complete.
// ---------------------------------------------------------------------------
template<typename T, int DTYPE, typename PT>
__global__ void edge_direct(
        const int* __restrict__ flag,
        const PT* __restrict__ Pd1, const PT* __restrict__ Ps1,
        const PT* __restrict__ Pd2, const PT* __restrict__ Ps2,
        const int* __restrict__ src, const int* __restrict__ dst,
        const T* __restrict__ g1, const T* __restrict__ be1,
        const T* __restrict__ W2, const T* __restrict__ b2,
        const T* __restrict__ g2, const T* __restrict__ be2,
        const T* __restrict__ W3, const T* __restrict__ b3,
        T* __restrict__ out, int E) {
    if (*flag != DTYPE) return;
    __shared__ float shH[64 * 132];    // h1 fp32; later reused as shT[64*66]
    __shared__ float shW2[128 * 66];   // W2 fp32 [k][c]
    float* shT = shH;

    const int t = threadIdx.x;
    const int e = t >> 2, q = t & 3;
    const int edge = blockIdx.x * 64 + e;
    const bool valid = edge < E;
    const int ec = valid ? edge : (E - 1);
    const int si = src[ec], di = dst[ec];

    // ---- stage W2 (128x64) into LDS fp32 ----
    for (int i = 0; i < 32; ++i) {
        int u = t + 256 * i;          // < 8192
        int k = u >> 6, c = u & 63;
        shW2[k * 66 + c] = cvt(W2[u]);
    }

    // ---- phase 1: gather + t1 + LN1 + GELU -> shH (fp32) ----
    float t1v[32];
    float sum = 0.f, ssq = 0.f;
    #pragma unroll
    for (int j = 0; j < 4; ++j) {
        int ch8 = j * 4 + q;          // chunks {q, q+4, q+8, q+12}
        float a[8], b[8];
        load8f(Pd1 + (size_t)si * 128 + ch8 * 8, a);
        load8f(Ps1 + (size_t)di * 128 + ch8 * 8, b);
        #pragma unroll
        for (int c = 0; c < 8; ++c) {
            float v = a[c] + b[c];    // b1 folded into Pd1
            t1v[j * 8 + c] = v;
            sum += v; ssq += v * v;
        }
    }
    sum += __shfl_xor(sum, 1); ssq += __shfl_xor(ssq, 1);
    sum += __shfl_xor(sum, 2); ssq += __shfl_xor(ssq, 2);
    float mu   = sum * (1.0f / 128.0f);
    float var  = fmaxf(ssq * (1.0f / 128.0f) - mu * mu, 0.0f);
    float rsig = rsqrtf(var + 1e-5f);

    // identity gather (bs folded into Pd2)
    float idv[16];
    #pragma unroll
    for (int j = 0; j < 2; ++j) {
        int ch8 = j * 4 + q;          // chunks {q, q+4}
        float a[8], b[8];
        load8f(Pd2 + (size_t)si * 64 + ch8 * 8, a);
        load8f(Ps2 + (size_t)di * 64 + ch8 * 8, b);
        #pragma unroll
        for (int c = 0; c < 8; ++c) idv[j * 8 + c] = a[c] + b[c];
    }

    #pragma unroll
    for (int j = 0; j < 4; ++j) {
        int ch8 = j * 4 + q;
        #pragma unroll
        for (int c = 0; c < 8; ++c) {
            int ch = ch8 * 8 + c;
            float h = (t1v[j * 8 + c] - mu) * rsig * cvt(g1[ch]) + cvt(be1[ch]);
            shH[e * 132 + ch] = gelu_exact(h);
        }
    }
    __syncthreads();

    // ---- phase 2: t2[e][c] = h1[e][:] . W2[:][c] + b2[c], per-thread dots ----
    // thread t: edge e = t>>2, channels c0 = (t&3)*16 .. +15
    float t2r[16];
    {
        const int c0 = q * 16;
        #pragma unroll
        for (int i = 0; i < 16; ++i) t2r[i] = 0.f;
        for (int k = 0; k < 128; ++k) {
            float hv = shH[e * 132 + k];
            #pragma unroll
            for (int i = 0; i < 16; ++i) t2r[i] += hv * shW2[k * 66 + c0 + i];
        }
        #pragma unroll
        for (int i = 0; i < 16; ++i) t2r[i] += cvt(b2[c0 + i]);
    }
    __syncthreads();   // all shH reads complete before reuse as shT
    {
        const int c0 = q * 16;
        #pragma unroll
        for (int i = 0; i < 16; ++i) shT[e * 66 + c0 + i] = t2r[i];
    }
    __syncthreads();

    // ---- phase 3: LN2 + identity + GELU + W3 dot ----
    float t2v[16];
    float s2 = 0.f, q2 = 0.f;
    #pragma unroll
    for (int j = 0; j < 2; ++j) {
        int base = (j * 4 + q) * 8;   // chunks {q, q+4}
        #pragma unroll
        for (int c = 0; c < 8; ++c) {
            float v = shT[e * 66 + base + c];
            t2v[j * 8 + c] = v;
            s2 += v; q2 += v * v;
        }
    }
    s2 += __shfl_xor(s2, 1); q2 += __shfl_xor(q2, 1);
    s2 += __shfl_xor(s2, 2); q2 += __shfl_xor(q2, 2);
    float mu2  = s2 * (1.0f / 64.0f);
    float var2 = fmaxf(q2 * (1.0f / 64.0f) - mu2 * mu2, 0.0f);
    float rs2  = rsqrtf(var2 + 1e-5f);

    float osum = 0.f;
    #pragma unroll
    for (int j = 0; j < 2; ++j) {
        int base = (j * 4 + q) * 8;
        #pragma unroll
        for (int c = 0; c < 8; ++c) {
            int ch = base + c;
            float v = (t2v[j * 8 + c] - mu2) * rs2 * cvt(g2[ch]) + cvt(be2[ch]);
            v += idv[j * 8 + c];
            v = gelu_exact(v);
            osum += v * cvt(W3[ch]);
        }
    }
    osum += __shfl_xor(osum, 1);
    osum += __shfl_xor(osum, 2);
    if (q == 0 && valid) out[edge] = (T)(osum + cvt(b3[0]));
}

// ---------------------------------------------------------------------------
template<typename PT>
static void launch_all(void* const* d_in, int E, int NDd, int NDs,
                       void* d_out, char* ws, hipStream_t stream) {
    PT* Pd1 = (PT*)ws;                                  ws += (size_t)NDd * 128 * sizeof(PT);
    PT* Ps1 = (PT*)ws;                                  ws += (size_t)NDs * 128 * sizeof(PT);
    PT* Pd2 = (PT*)ws;                                  ws += (size_t)NDd * 64 * sizeof(PT);
    PT* Ps2 = (PT*)ws;                                  ws += (size_t)NDs * 64 * sizeof(PT);
    int* flag = (int*)ws;

    detect_dtype<<<1, 64, 0, stream>>>((const uint32_t*)d_in[0], flag);

    int gbd = (NDd + 3) / 4, gbs = (NDs + 3) / 4;
    // drug side: rows 0..255 of W1/Ws, biases folded
    prep_direct<float, 1, PT><<<gbd, 192, 0, stream>>>(flag, (const float*)d_in[0],
        (const float*)d_in[4], (const float*)d_in[14],
        (const float*)d_in[5], (const float*)d_in[15], Pd1, Pd2, 0, 1, NDd);
    prep_direct<bf16_t, 2, PT><<<gbd, 192, 0, stream>>>(flag, (const bf16_t*)d_in[0],
        (const bf16_t*)d_in[4], (const bf16_t*)d_in[14],
        (const bf16_t*)d_in[5], (const bf16_t*)d_in[15], Pd1, Pd2, 0, 1, NDd);
    // disease side: rows 256..511, no bias
    prep_direct<float, 1, PT><<<gbs, 192, 0, stream>>>(flag, (const float*)d_in[1],
        (const float*)d_in[4], (const float*)d_in[14],
        (const float*)d_in[5], (const float*)d_in[15], Ps1, Ps2, 256, 0, NDs);
    prep_direct<bf16_t, 2, PT><<<gbs, 192, 0, stream>>>(flag, (const bf16_t*)d_in[1],
        (const bf16_t*)d_in[4], (const bf16_t*)d_in[14],
        (const bf16_t*)d_in[5], (const bf16_t*)d_in[15], Ps1, Ps2, 256, 0, NDs);

    int geb = (E + 63) / 64;
    edge_direct<float, 1, PT><<<geb, 256, 0, stream>>>(flag, Pd1, Ps1, Pd2, Ps2,
        (const int*)d_in[2], (const int*)d_in[3],
        (const float*)d_in[6], (const float*)d_in[7],
        (const float*)d_in[8], (const float*)d_in[9],
        (const float*)d_in[10], (const float*)d_in[11],
        (const float*)d_in[12], (const float*)d_in[13], (float*)d_out, E);
    edge_direct<bf16_t, 2, PT><<<geb, 256, 0, stream>>>(flag, Pd1, Ps1, Pd2, Ps2,
        (const int*)d_in[2], (const int*)d_in[3],
        (const bf16_t*)d_in[6], (const bf16_t*)d_in[7],
        (const bf16_t*)d_in[8], (const bf16_t*)d_in[9],
        (const bf16_t*)d_in[10], (const bf16_t*)d_in[11],
        (const bf16_t*)d_in[12], (const bf16_t*)d_in[13], (bf16_t*)d_out, E);
}

extern "C" void kernel_launch(void* const* d_in, const int* in_sizes, int n_in,
                              void* d_out, int out_size, void* d_ws, size_t ws_size,
                              hipStream_t stream) {
    const int E   = in_sizes[2];
    const int NDd = in_sizes[0] / 256;
    const int NDs = in_sizes[1] / 256;

    size_t needF = (size_t)(NDd + NDs) * 192 * 4 + 256;   // fp32 tables + flag
    if (ws_size >= needF)
        launch_all<float>(d_in, E, NDd, NDs, d_out, (char*)d_ws, stream);
    else
        launch_all<bf16_t>(d_in, E, NDd, NDs, d_out, (char*)d_ws, stream);
}

// Round 6
// 349.085 us; speedup vs baseline: 2.0909x; 2.0909x over previous
//
#include <hip/hip_runtime.h>
#include <hip/hip_bf16.h>
#include <stdint.h>

typedef __bf16 bf16_t;
typedef __attribute__((ext_vector_type(8))) __bf16 bf16x8;
typedef __attribute__((ext_vector_type(4))) float f32x4;

typedef __attribute__((address_space(3))) void lds_void;
typedef const __attribute__((address_space(1))) void glb_void;

__device__ __forceinline__ void async_copy16(const void* g, void* l) {
    __builtin_amdgcn_global_load_lds((glb_void*)g, (lds_void*)l, 16, 0, 0);
}

__device__ __forceinline__ float cvt(float v)  { return v; }
__device__ __forceinline__ float cvt(bf16_t v) { return (float)v; }

template<typename PT>
__device__ __forceinline__ void load8f(const PT* p, float o[8]) {
    if constexpr (sizeof(PT) == 4) {
        const float4* q = (const float4*)p;
        float4 a = q[0], b = q[1];
        o[0]=a.x; o[1]=a.y; o[2]=a.z; o[3]=a.w;
        o[4]=b.x; o[5]=b.y; o[6]=b.z; o[7]=b.w;
    } else {
        bf16x8 v = *(const bf16x8*)p;
        #pragma unroll
        for (int i = 0; i < 8; ++i) o[i] = (float)v[i];
    }
}

// A&S 7.1.26 erf approximation, |abs err| <= 1.5e-7
__device__ __forceinline__ float erf_approx(float x) {
    float ax = fabsf(x);
    float t  = __builtin_amdgcn_rcpf(1.0f + 0.3275911f * ax);
    float y  = t * (0.254829592f + t * (-0.284496736f + t * (1.421413741f +
               t * (-1.453152027f + t * 1.061405429f))));
    float r  = 1.0f - y * __expf(-ax * ax);
    return copysignf(r, x);
}
__device__ __forceinline__ float gelu_exact(float x) {
    return 0.5f * x * (1.0f + erf_approx(x * 0.70710678118654752f));
}

// ---------------------------------------------------------------------------
// Kernel 0: dtype detection. flag: 1 = fp32, 2 = bf16.
// ---------------------------------------------------------------------------
__global__ void detect_dtype(const uint32_t* __restrict__ bits, int* __restrict__ flag) {
    int l = threadIdx.x;
    int cnt = 0;
    for (int i = l; i < 256; i += 64) {
        float v = __uint_as_float(bits[i]);
        if (v == v && fabsf(v) < 1024.0f) cnt++;
    }
    cnt += __shfl_xor(cnt, 1);  cnt += __shfl_xor(cnt, 2);
    cnt += __shfl_xor(cnt, 4);  cnt += __shfl_xor(cnt, 8);
    cnt += __shfl_xor(cnt, 16); cnt += __shfl_xor(cnt, 32);
    if (l == 0) *flag = (cnt >= 128) ? 1 : 2;
}

// ---------------------------------------------------------------------------
// Kernel 1: pack/transpose weights (bf16 hi + lo residual for fp32 inputs).
// WT*[192][256]: rows 0..127 = W1 cols, 128..191 = Ws cols. W2T[64][128]=W2^T.
// ---------------------------------------------------------------------------
template<typename T, int DTYPE>
__global__ void prep_weights(const int* __restrict__ flag,
                             const T* __restrict__ W1, const T* __restrict__ Wsc,
                             const T* __restrict__ W2,
                             bf16_t* __restrict__ WTdh, bf16_t* __restrict__ WTdl,
                             bf16_t* __restrict__ WTsh, bf16_t* __restrict__ WTsl,
                             bf16_t* __restrict__ W2Th, bf16_t* __restrict__ W2Tl) {
    if (*flag != DTYPE) return;
    constexpr bool F32 = (sizeof(T) == 4);
    int t = blockIdx.x * 256 + threadIdx.x;
    if (t < 192 * 256) {
        int n = t >> 8, k = t & 255;
        float vd = (n < 128) ? cvt(W1[k * 128 + n])         : cvt(Wsc[k * 64 + (n - 128)]);
        float vs = (n < 128) ? cvt(W1[(256 + k) * 128 + n]) : cvt(Wsc[(256 + k) * 64 + (n - 128)]);
        bf16_t dh = (bf16_t)vd, sh = (bf16_t)vs;
        WTdh[t] = dh; WTsh[t] = sh;
        if constexpr (F32) { WTdl[t] = (bf16_t)(vd - (float)dh); WTsl[t] = (bf16_t)(vs - (float)sh); }
        else               { WTdl[t] = (bf16_t)0.f;              WTsl[t] = (bf16_t)0.f; }
    } else {
        int u = t - 192 * 256;
        if (u < 64 * 128) {
            int n = u >> 7, k = u & 127;
            float v = cvt(W2[k * 64 + n]);
            bf16_t h = (bf16_t)v;
            W2Th[u] = h;
            if constexpr (F32) W2Tl[u] = (bf16_t)(v - (float)h);
            else               W2Tl[u] = (bf16_t)0.f;
        }
    }
}

// ---------------------------------------------------------------------------
// Kernel 2: per-node projection GEMM (split-MFMA, ~fp32-exact).
// P1[m][0..127] fp32, P2[m][0..63] fp32 = feat[m][:] @ WT^T (+bias drug side).
// BM=128, N=192, K=256, BK=32. MFMA 16x16x32:
//   A: m=lane&15, k=(lane>>4)*8+j ; C/D: col=lane&15, row=(lane>>4)*4+reg.
// ---------------------------------------------------------------------------
template<typename T, int DTYPE, typename PT>
__global__ __launch_bounds__(256) void prep_gemm(
        const int* __restrict__ flag,
        const T* __restrict__ feat,
        const bf16_t* __restrict__ WTh, const bf16_t* __restrict__ WTl,
        const T* __restrict__ b1, const T* __restrict__ bsv,
        PT* __restrict__ P1, PT* __restrict__ P2, int fold_bias, int ND) {
    if (*flag != DTYPE) return;
    constexpr bool F32 = (sizeof(T) == 4);
    __shared__ bf16_t shAhi[128 * 32];
    __shared__ bf16_t shAlo[F32 ? 128 * 32 : 1];
    __shared__ bf16_t shBhi[192 * 32];
    __shared__ bf16_t shBlo[F32 ? 192 * 32 : 1];

    const int t = threadIdx.x;
    const int w = t >> 6, l = t & 63;
    const int m0 = blockIdx.x * 128;
    const int lm = l & 15, kq = (l >> 4) * 8;

    f32x4 acc[2][12] = {};

    for (int k0 = 0; k0 < 256; k0 += 32) {
        if (k0) __syncthreads();
        // ---- stage A tile: 128 rows x 32 k ----
        if constexpr (!F32) {
            #pragma unroll
            for (int j = 0; j < 2; ++j) {
                int row0 = 32 * w + 16 * j;
                int gr = min(m0 + row0 + (l >> 2), ND - 1);
                async_copy16(feat + (size_t)gr * 256 + k0 + (l & 3) * 8, &shAhi[row0 * 32]);
            }
        } else {
            int r = t >> 1, half = t & 1;
            int gr = min(m0 + r, ND - 1);
            const float4* gp = (const float4*)(feat + (size_t)gr * 256 + k0 + half * 16);
            float f[16];
            #pragma unroll
            for (int j = 0; j < 4; ++j) {
                float4 v = gp[j];
                f[j*4]=v.x; f[j*4+1]=v.y; f[j*4+2]=v.z; f[j*4+3]=v.w;
            }
            bf16x8 hi0, hi1, lo0, lo1;
            #pragma unroll
            for (int j = 0; j < 8; ++j) {
                bf16_t h0 = (bf16_t)f[j], h1 = (bf16_t)f[8+j];
                hi0[j] = h0; lo0[j] = (bf16_t)(f[j] - (float)h0);
                hi1[j] = h1; lo1[j] = (bf16_t)(f[8+j] - (float)h1);
            }
            *(bf16x8*)&shAhi[r * 32 + half * 16]     = hi0;
            *(bf16x8*)&shAhi[r * 32 + half * 16 + 8] = hi1;
            *(bf16x8*)&shAlo[r * 32 + half * 16]     = lo0;
            *(bf16x8*)&shAlo[r * 32 + half * 16 + 8] = lo1;
        }
        // ---- stage B tile: 192 rows x 32 k ----
        #pragma unroll
        for (int j = 0; j < 3; ++j) {
            int row0 = 48 * w + 16 * j;
            async_copy16(WTh + (size_t)(row0 + (l >> 2)) * 256 + k0 + (l & 3) * 8, &shBhi[row0 * 32]);
            if constexpr (F32)
                async_copy16(WTl + (size_t)(row0 + (l >> 2)) * 256 + k0 + (l & 3) * 8, &shBlo[row0 * 32]);
        }
        __syncthreads();

        bf16x8 ahi[2], alo[2];
        #pragma unroll
        for (int i = 0; i < 2; ++i) {
            ahi[i] = *(const bf16x8*)&shAhi[((2 * w + i) * 16 + lm) * 32 + kq];
            if constexpr (F32)
                alo[i] = *(const bf16x8*)&shAlo[((2 * w + i) * 16 + lm) * 32 + kq];
        }
        #pragma unroll
        for (int j = 0; j < 12; ++j) {
            bf16x8 bhi = *(const bf16x8*)&shBhi[(j * 16 + lm) * 32 + kq];
            #pragma unroll
            for (int i = 0; i < 2; ++i)
                acc[i][j] = __builtin_amdgcn_mfma_f32_16x16x32_bf16(ahi[i], bhi, acc[i][j], 0, 0, 0);
            if constexpr (F32) {
                bf16x8 blo = *(const bf16x8*)&shBlo[(j * 16 + lm) * 32 + kq];
                #pragma unroll
                for (int i = 0; i < 2; ++i) {
                    acc[i][j] = __builtin_amdgcn_mfma_f32_16x16x32_bf16(alo[i], bhi, acc[i][j], 0, 0, 0);
                    acc[i][j] = __builtin_amdgcn_mfma_f32_16x16x32_bf16(ahi[i], blo, acc[i][j], 0, 0, 0);
                }
            }
        }
    }

    #pragma unroll
    for (int i = 0; i < 2; ++i) {
        #pragma unroll
        for (int j = 0; j < 12; ++j) {
            int col = j * 16 + lm;
            float bias = 0.0f;
            if (fold_bias) bias = (col < 128) ? cvt(b1[col]) : cvt(bsv[col - 128]);
            #pragma unroll
            for (int r = 0; r < 4; ++r) {
                int row = m0 + (2 * w + i) * 16 + (l >> 4) * 4 + r;
                if (row < ND) {
                    float v = acc[i][j][r] + bias;
                    if (col < 128) P1[(size_t)row * 128 + col] = (PT)v;
                    else           P2[(size_t)row * 64 + (col - 128)] = (PT)v;
                }
            }
        }
    }
}

// ---------------------------------------------------------------------------
// Kernel 3: fused edge kernel. 64 edges/block, 256 threads.
// Phase 2 = split MFMA, two-pass shH (hi then lo from registers):
//   pass a: ahi*bhi + ahi*blo ; pass b: alo*bhi.  All intermediates <=2^-17.
// ---------------------------------------------------------------------------
template<typename T, int DTYPE, typename PT>
__global__ __launch_bounds__(256) void edge_mfma2(
        const int* __restrict__ flag,
        const PT* __restrict__ Pd1, const PT* __restrict__ Ps1,
        const PT* __restrict__ Pd2, const PT* __restrict__ Ps2,
        const bf16_t* __restrict__ W2Th, const bf16_t* __restrict__ W2Tl,
        const int* __restrict__ src, const int* __restrict__ dst,
        const T* __restrict__ g1, const T* __restrict__ be1,
        const T* __restrict__ b2, const T* __restrict__ g2,
        const T* __restrict__ be2,
        const T* __restrict__ W3, const T* __restrict__ b3,
        T* __restrict__ out, int E) {
    if (*flag != DTYPE) return;
    __shared__ bf16_t shH[64 * 136];    // h1 hi (pass a) then lo (pass b)
    __shared__ bf16_t shWhi[64 * 136];  // W2^T hi [n][k]
    __shared__ bf16_t shWlo[64 * 136];  // W2^T lo
    __shared__ float  shT[64 * 66];     // t2 fp32

    const int t = threadIdx.x;
    const int w = t >> 6, l = t & 63;
    const int e = t >> 2, q = t & 3;
    const int edge = blockIdx.x * 64 + e;
    const bool valid = edge < E;
    const int ec = valid ? edge : (E - 1);
    const int si = src[ec], di = dst[ec];

    // ---- stage W2T hi/lo ----
    {
        int row = t >> 2, c4 = t & 3;
        const bf16x8* gh = (const bf16x8*)(W2Th + row * 128 + c4 * 32);
        const bf16x8* gl = (const bf16x8*)(W2Tl + row * 128 + c4 * 32);
        bf16x8* dh = (bf16x8*)&shWhi[row * 136 + c4 * 32];
        bf16x8* dl = (bf16x8*)&shWlo[row * 136 + c4 * 32];
        dh[0] = gh[0]; dh[1] = gh[1]; dh[2] = gh[2]; dh[3] = gh[3];
        dl[0] = gl[0]; dl[1] = gl[1]; dl[2] = gl[2]; dl[3] = gl[3];
    }

    // ---- phase 1: fp32 gather + t1 + LN1 + GELU -> shH(hi), hlo in regs ----
    float t1v[32];
    float sum = 0.f, ssq = 0.f;
    #pragma unroll
    for (int j = 0; j < 4; ++j) {
        int ch8 = j * 4 + q;
        float a[8], b[8];
        load8f(Pd1 + (size_t)si * 128 + ch8 * 8, a);
        load8f(Ps1 + (size_t)di * 128 + ch8 * 8, b);
        #pragma unroll
        for (int c = 0; c < 8; ++c) {
            float v = a[c] + b[c];    // b1 folded into Pd1
            t1v[j * 8 + c] = v;
            sum += v; ssq += v * v;
        }
    }
    sum += __shfl_xor(sum, 1); ssq += __shfl_xor(ssq, 1);
    sum += __shfl_xor(sum, 2); ssq += __shfl_xor(ssq, 2);
    float mu   = sum * (1.0f / 128.0f);
    float var  = fmaxf(ssq * (1.0f / 128.0f) - mu * mu, 0.0f);
    float rsig = rsqrtf(var + 1e-5f);

    // identity gather, fp32 exact (bs folded into Pd2)
    float idv[16];
    #pragma unroll
    for (int j = 0; j < 2; ++j) {
        int ch8 = j * 4 + q;
        float a[8], b[8];
        load8f(Pd2 + (size_t)si * 64 + ch8 * 8, a);
        load8f(Ps2 + (size_t)di * 64 + ch8 * 8, b);
        #pragma unroll
        for (int c = 0; c < 8; ++c) idv[j * 8 + c] = a[c] + b[c];
    }

    bf16x8 hlov[4];
    #pragma unroll
    for (int j = 0; j < 4; ++j) {
        int ch8 = j * 4 + q;
        bf16x8 hhi;
        #pragma unroll
        for (int c = 0; c < 8; ++c) {
            int ch = ch8 * 8 + c;
            float h = (t1v[j * 8 + c] - mu) * rsig * cvt(g1[ch]) + cvt(be1[ch]);
            h = gelu_exact(h);
            bf16_t hb = (bf16_t)h;
            hhi[c] = hb;
            hlov[j][c] = (bf16_t)(h - (float)hb);
        }
        *(bf16x8*)&shH[e * 136 + ch8 * 8] = hhi;
    }
    __syncthreads();

    // ---- phase 2, pass a: acc = ahi*bhi + ahi*blo ----
    const int lm = l & 15, kq = (l >> 4) * 8;
    f32x4 acc[4] = {};
    #pragma unroll
    for (int k0 = 0; k0 < 128; k0 += 32) {
        bf16x8 ahi = *(const bf16x8*)&shH[(w * 16 + lm) * 136 + k0 + kq];
        #pragma unroll
        for (int n = 0; n < 4; ++n) {
            bf16x8 bhi = *(const bf16x8*)&shWhi[(n * 16 + lm) * 136 + k0 + kq];
            bf16x8 blo = *(const bf16x8*)&shWlo[(n * 16 + lm) * 136 + k0 + kq];
            acc[n] = __builtin_amdgcn_mfma_f32_16x16x32_bf16(ahi, bhi, acc[n], 0, 0, 0);
            acc[n] = __builtin_amdgcn_mfma_f32_16x16x32_bf16(ahi, blo, acc[n], 0, 0, 0);
        }
    }
    __syncthreads();   // pass-a reads of shH done
    #pragma unroll
    for (int j = 0; j < 4; ++j)
        *(bf16x8*)&shH[e * 136 + (j * 4 + q) * 8] = hlov[j];
    __syncthreads();   // hlo visible
    // ---- phase 2, pass b: acc += alo*bhi ----
    #pragma unroll
    for (int k0 = 0; k0 < 128; k0 += 32) {
        bf16x8 alo = *(const bf16x8*)&shH[(w * 16 + lm) * 136 + k0 + kq];
        #pragma unroll
        for (int n = 0; n < 4; ++n) {
            bf16x8 bhi = *(const bf16x8*)&shWhi[(n * 16 + lm) * 136 + k0 + kq];
            acc[n] = __builtin_amdgcn_mfma_f32_16x16x32_bf16(alo, bhi, acc[n], 0, 0, 0);
        }
    }
    #pragma unroll
    for (int n = 0; n < 4; ++n) {
        int col = n * 16 + lm;
        float b2v = cvt(b2[col]);
        #pragma unroll
        for (int r = 0; r < 4; ++r) {
            int row = w * 16 + (l >> 4) * 4 + r;
            shT[row * 66 + col] = acc[n][r] + b2v;
        }
    }
    __syncthreads();

    // ---- phase 3: LN2 + identity + GELU + W3 dot ----
    float t2v[16];
    float s2 = 0.f, q2 = 0.f;
    #pragma unroll
    for (int j = 0; j < 2; ++j) {
        int base = (j * 4 + q) * 8;
        #pragma unroll
        for (int c = 0; c < 8; ++c) {
            float v = shT[e * 66 + base + c];
            t2v[j * 8 + c] = v;
            s2 += v; q2 += v * v;
        }
    }
    s2 += __shfl_xor(s2, 1); q2 += __shfl_xor(q2, 1);
    s2 += __shfl_xor(s2, 2); q2 += __shfl_xor(q2, 2);
    float mu2  = s2 * (1.0f / 64.0f);
    float var2 = fmaxf(q2 * (1.0f / 64.0f) - mu2 * mu2, 0.0f);
    float rs2  = rsqrtf(var2 + 1e-5f);

    float osum = 0.f;
    #pragma unroll
    for (int j = 0; j < 2; ++j) {
        int base = (j * 4 + q) * 8;
        #pragma unroll
        for (int c = 0; c < 8; ++c) {
            int ch = base + c;
            float v = (t2v[j * 8 + c] - mu2) * rs2 * cvt(g2[ch]) + cvt(be2[ch]);
            v += idv[j * 8 + c];
            v = gelu_exact(v);
            osum += v * cvt(W3[ch]);
        }
    }
    osum += __shfl_xor(osum, 1);
    osum += __shfl_xor(osum, 2);
    if (q == 0 && valid) out[edge] = (T)(osum + cvt(b3[0]));
}

// ---------------------------------------------------------------------------
template<typename PT>
static void launch_all(void* const* d_in, int E, int NDd, int NDs,
                       void* d_out, char* ws, hipStream_t stream) {
    // small fixed region first
    bf16_t* WTdh = (bf16_t*)ws;                     ws += 192 * 256 * 2;
    bf16_t* WTdl = (bf16_t*)ws;                     ws += 192 * 256 * 2;
    bf16_t* WTsh = (bf16_t*)ws;                     ws += 192 * 256 * 2;
    bf16_t* WTsl = (bf16_t*)ws;                     ws += 192 * 256 * 2;
    bf16_t* W2Th = (bf16_t*)ws;                     ws += 64 * 128 * 2;
    bf16_t* W2Tl = (bf16_t*)ws;                     ws += 64 * 128 * 2;
    int*    flag = (int*)ws;                        ws += 256;
    PT* Pd1 = (PT*)ws;                              ws += (size_t)NDd * 128 * sizeof(PT);
    PT* Ps1 = (PT*)ws;                              ws += (size_t)NDs * 128 * sizeof(PT);
    PT* Pd2 = (PT*)ws;                              ws += (size_t)NDd * 64 * sizeof(PT);
    PT* Ps2 = (PT*)ws;

    detect_dtype<<<1, 64, 0, stream>>>((const uint32_t*)d_in[0], flag);

    prep_weights<float, 1><<<224, 256, 0, stream>>>(flag,
        (const float*)d_in[4], (const float*)d_in[14], (const float*)d_in[8],
        WTdh, WTdl, WTsh, WTsl, W2Th, W2Tl);
    prep_weights<bf16_t, 2><<<224, 256, 0, stream>>>(flag,
        (const bf16_t*)d_in[4], (const bf16_t*)d_in[14], (const bf16_t*)d_in[8],
        WTdh, WTdl, WTsh, WTsl, W2Th, W2Tl);

    int gbd = (NDd + 127) / 128, gbs = (NDs + 127) / 128;
    prep_gemm<float, 1, PT><<<gbd, 256, 0, stream>>>(flag, (const float*)d_in[0], WTdh, WTdl,
        (const float*)d_in[5], (const float*)d_in[15], Pd1, Pd2, 1, NDd);
    prep_gemm<bf16_t, 2, PT><<<gbd, 256, 0, stream>>>(flag, (const bf16_t*)d_in[0], WTdh, WTdl,
        (const bf16_t*)d_in[5], (const bf16_t*)d_in[15], Pd1, Pd2, 1, NDd);
    prep_gemm<float, 1, PT><<<gbs, 256, 0, stream>>>(flag, (const float*)d_in[1], WTsh, WTsl,
        (const float*)d_in[5], (const float*)d_in[15], Ps1, Ps2, 0, NDs);
    prep_gemm<bf16_t, 2, PT><<<gbs, 256, 0, stream>>>(flag, (const bf16_t*)d_in[1], WTsh, WTsl,
        (const bf16_t*)d_in[5], (const bf16_t*)d_in[15], Ps1, Ps2, 0, NDs);

    int geb = (E + 63) / 64;
    edge_mfma2<float, 1, PT><<<geb, 256, 0, stream>>>(flag, Pd1, Ps1, Pd2, Ps2, W2Th, W2Tl,
        (const int*)d_in[2], (const int*)d_in[3],
        (const float*)d_in[6], (const float*)d_in[7], (const float*)d_in[9],
        (const float*)d_in[10], (const float*)d_in[11],
        (const float*)d_in[12], (const float*)d_in[13], (float*)d_out, E);
    edge_mfma2<bf16_t, 2, PT><<<geb, 256, 0, stream>>>(flag, Pd1, Ps1, Pd2, Ps2, W2Th, W2Tl,
        (const int*)d_in[2], (const int*)d_in[3],
        (const bf16_t*)d_in[6], (const bf16_t*)d_in[7], (const bf16_t*)d_in[9],
        (const bf16_t*)d_in[10], (const bf16_t*)d_in[11],
        (const bf16_t*)d_in[12], (const bf16_t*)d_in[13], (bf16_t*)d_out, E);
}

extern "C" void kernel_launch(void* const* d_in, const int* in_sizes, int n_in,
                              void* d_out, int out_size, void* d_ws, size_t ws_size,
                              hipStream_t stream) {
    const int E   = in_sizes[2];
    const int NDd = in_sizes[0] / 256;
    const int NDs = in_sizes[1] / 256;

    size_t fixed = 4 * 192 * 256 * 2 + 2 * 64 * 128 * 2 + 256;
    size_t needF = fixed + (size_t)(NDd + NDs) * 192 * 4;   // fp32 P tables
    if (ws_size >= needF)
        launch_all<float>(d_in, E, NDd, NDs, d_out, (char*)d_ws, stream);
    else
        launch_all<bf16_t>(d_in, E, NDd, NDs, d_out, (char*)d_ws, stream);
}

// Round 8
// 334.665 us; speedup vs baseline: 2.1810x; 1.0431x over previous
//
#include <hip/hip_runtime.h>
#include <hip/hip_bf16.h>
#include <stdint.h>

typedef __bf16 bf16_t;
typedef __attribute__((ext_vector_type(8))) __bf16 bf16x8;
typedef __attribute__((ext_vector_type(4))) float f32x4;

typedef __attribute__((address_space(3))) void lds_void;
typedef const __attribute__((address_space(1))) void glb_void;

__device__ __forceinline__ void async_copy16(const void* g, void* l) {
    __builtin_amdgcn_global_load_lds((glb_void*)g, (lds_void*)l, 16, 0, 0);
}

__device__ __forceinline__ float cvt(float v)  { return v; }
__device__ __forceinline__ float cvt(bf16_t v) { return (float)v; }

template<typename PT>
__device__ __forceinline__ void load8f(const PT* p, float o[8]) {
    if constexpr (sizeof(PT) == 4) {
        const float4* q = (const float4*)p;
        float4 a = q[0], b = q[1];
        o[0]=a.x; o[1]=a.y; o[2]=a.z; o[3]=a.w;
        o[4]=b.x; o[5]=b.y; o[6]=b.z; o[7]=b.w;
    } else {
        bf16x8 v = *(const bf16x8*)p;
        #pragma unroll
        for (int i = 0; i < 8; ++i) o[i] = (float)v[i];
    }
}

// A&S 7.1.26 erf approximation, |abs err| <= 1.5e-7
__device__ __forceinline__ float erf_approx(float x) {
    float ax = fabsf(x);
    float t  = __builtin_amdgcn_rcpf(1.0f + 0.3275911f * ax);
    float y  = t * (0.254829592f + t * (-0.284496736f + t * (1.421413741f +
               t * (-1.453152027f + t * 1.061405429f))));
    float r  = 1.0f - y * __expf(-ax * ax);
    return copysignf(r, x);
}
__device__ __forceinline__ float gelu_exact(float x) {
    return 0.5f * x * (1.0f + erf_approx(x * 0.70710678118654752f));
}

// ---------------------------------------------------------------------------
// Kernel 0: dtype detection. flag: 1 = fp32, 2 = bf16.
// ---------------------------------------------------------------------------
__global__ void detect_dtype(const uint32_t* __restrict__ bits, int* __restrict__ flag) {
    int l = threadIdx.x;
    int cnt = 0;
    for (int i = l; i < 256; i += 64) {
        float v = __uint_as_float(bits[i]);
        if (v == v && fabsf(v) < 1024.0f) cnt++;
    }
    cnt += __shfl_xor(cnt, 1);  cnt += __shfl_xor(cnt, 2);
    cnt += __shfl_xor(cnt, 4);  cnt += __shfl_xor(cnt, 8);
    cnt += __shfl_xor(cnt, 16); cnt += __shfl_xor(cnt, 32);
    if (l == 0) *flag = (cnt >= 128) ? 1 : 2;
}

// ---------------------------------------------------------------------------
// Kernel 1: pack/transpose weights (bf16 hi + lo residual). Verbatim R6.
// WT*[192][256]: rows 0..127 = W1 cols, 128..191 = Ws cols. W2T[64][128]=W2^T.
// ---------------------------------------------------------------------------
template<typename T, int DTYPE>
__global__ void prep_weights(const int* __restrict__ flag,
                             const T* __restrict__ W1, const T* __restrict__ Wsc,
                             const T* __restrict__ W2,
                             bf16_t* __restrict__ WTdh, bf16_t* __restrict__ WTdl,
                             bf16_t* __restrict__ WTsh, bf16_t* __restrict__ WTsl,
                             bf16_t* __restrict__ W2Th, bf16_t* __restrict__ W2Tl) {
    if (*flag != DTYPE) return;
    constexpr bool F32 = (sizeof(T) == 4);
    int t = blockIdx.x * 256 + threadIdx.x;
    if (t < 192 * 256) {
        int n = t >> 8, k = t & 255;
        float vd = (n < 128) ? cvt(W1[k * 128 + n])         : cvt(Wsc[k * 64 + (n - 128)]);
        float vs = (n < 128) ? cvt(W1[(256 + k) * 128 + n]) : cvt(Wsc[(256 + k) * 64 + (n - 128)]);
        bf16_t dh = (bf16_t)vd, sh = (bf16_t)vs;
        WTdh[t] = dh; WTsh[t] = sh;
        if constexpr (F32) { WTdl[t] = (bf16_t)(vd - (float)dh); WTsl[t] = (bf16_t)(vs - (float)sh); }
        else               { WTdl[t] = (bf16_t)0.f;              WTsl[t] = (bf16_t)0.f; }
    } else {
        int u = t - 192 * 256;
        if (u < 64 * 128) {
            int n = u >> 7, k = u & 127;
            float v = cvt(W2[k * 64 + n]);
            bf16_t h = (bf16_t)v;
            W2Th[u] = h;
            if constexpr (F32) W2Tl[u] = (bf16_t)(v - (float)h);
            else               W2Tl[u] = (bf16_t)0.f;
        }
    }
}

// ---------------------------------------------------------------------------
// Kernel 2: per-node projection GEMM — R6's prep_gemm body VERBATIM; the ONLY
// change is the blockIdx-based side-select preamble so both sides run in one
// dispatch (782 blocks ≈ 3/CU instead of 2 serialized 391-block dispatches).
// BM=128, N=192, K=256, BK=32. MFMA 16x16x32:
//   A: m=lane&15, k=(lane>>4)*8+j ; C/D: col=lane&15, row=(lane>>4)*4+reg.
// ---------------------------------------------------------------------------
template<typename T, int DTYPE, typename PT>
__global__ __launch_bounds__(256) void prep_gemm_m(
        const int* __restrict__ flag,
        const T* __restrict__ featD, const T* __restrict__ featS,
        const bf16_t* __restrict__ WTdh, const bf16_t* __restrict__ WTdl,
        const bf16_t* __restrict__ WTsh, const bf16_t* __restrict__ WTsl,
        const T* __restrict__ b1, const T* __restrict__ bsv,
        PT* __restrict__ Pd1, PT* __restrict__ Pd2,
        PT* __restrict__ Ps1, PT* __restrict__ Ps2,
        int NDd, int NDs, int gbd) {
    if (*flag != DTYPE) return;
    constexpr bool F32 = (sizeof(T) == 4);
    __shared__ bf16_t shAhi[128 * 32];
    __shared__ bf16_t shAlo[F32 ? 128 * 32 : 1];
    __shared__ bf16_t shBhi[192 * 32];
    __shared__ bf16_t shBlo[F32 ? 192 * 32 : 1];

    // ---- side select (block-uniform) ----
    const bool drug = (int)blockIdx.x < gbd;
    const T* feat = drug ? featD : featS;
    const bf16_t* WTh = drug ? WTdh : WTsh;
    const bf16_t* WTl = drug ? WTdl : WTsl;
    PT* P1 = drug ? Pd1 : Ps1;
    PT* P2 = drug ? Pd2 : Ps2;
    const int ND = drug ? NDd : NDs;
    const int fold_bias = drug ? 1 : 0;
    const int m0 = (drug ? (int)blockIdx.x : (int)blockIdx.x - gbd) * 128;

    const int t = threadIdx.x;
    const int w = t >> 6, l = t & 63;
    const int lm = l & 15, kq = (l >> 4) * 8;

    f32x4 acc[2][12] = {};

    for (int k0 = 0; k0 < 256; k0 += 32) {
        if (k0) __syncthreads();
        // ---- stage A tile: 128 rows x 32 k ----
        if constexpr (!F32) {
            #pragma unroll
            for (int j = 0; j < 2; ++j) {
                int row0 = 32 * w + 16 * j;
                int gr = min(m0 + row0 + (l >> 2), ND - 1);
                async_copy16(feat + (size_t)gr * 256 + k0 + (l & 3) * 8, &shAhi[row0 * 32]);
            }
        } else {
            int r = t >> 1, half = t & 1;
            int gr = min(m0 + r, ND - 1);
            const float4* gp = (const float4*)(feat + (size_t)gr * 256 + k0 + half * 16);
            float f[16];
            #pragma unroll
            for (int j = 0; j < 4; ++j) {
                float4 v = gp[j];
                f[j*4]=v.x; f[j*4+1]=v.y; f[j*4+2]=v.z; f[j*4+3]=v.w;
            }
            bf16x8 hi0, hi1, lo0, lo1;
            #pragma unroll
            for (int j = 0; j < 8; ++j) {
                bf16_t h0 = (bf16_t)f[j], h1 = (bf16_t)f[8+j];
                hi0[j] = h0; lo0[j] = (bf16_t)(f[j] - (float)h0);
                hi1[j] = h1; lo1[j] = (bf16_t)(f[8+j] - (float)h1);
            }
            *(bf16x8*)&shAhi[r * 32 + half * 16]     = hi0;
            *(bf16x8*)&shAhi[r * 32 + half * 16 + 8] = hi1;
            *(bf16x8*)&shAlo[r * 32 + half * 16]     = lo0;
            *(bf16x8*)&shAlo[r * 32 + half * 16 + 8] = lo1;
        }
        // ---- stage B tile: 192 rows x 32 k ----
        #pragma unroll
        for (int j = 0; j < 3; ++j) {
            int row0 = 48 * w + 16 * j;
            async_copy16(WTh + (size_t)(row0 + (l >> 2)) * 256 + k0 + (l & 3) * 8, &shBhi[row0 * 32]);
            if constexpr (F32)
                async_copy16(WTl + (size_t)(row0 + (l >> 2)) * 256 + k0 + (l & 3) * 8, &shBlo[row0 * 32]);
        }
        __syncthreads();

        bf16x8 ahi[2], alo[2];
        #pragma unroll
        for (int i = 0; i < 2; ++i) {
            ahi[i] = *(const bf16x8*)&shAhi[((2 * w + i) * 16 + lm) * 32 + kq];
            if constexpr (F32)
                alo[i] = *(const bf16x8*)&shAlo[((2 * w + i) * 16 + lm) * 32 + kq];
        }
        #pragma unroll
        for (int j = 0; j < 12; ++j) {
            bf16x8 bhi = *(const bf16x8*)&shBhi[(j * 16 + lm) * 32 + kq];
            #pragma unroll
            for (int i = 0; i < 2; ++i)
                acc[i][j] = __builtin_amdgcn_mfma_f32_16x16x32_bf16(ahi[i], bhi, acc[i][j], 0, 0, 0);
            if constexpr (F32) {
                bf16x8 blo = *(const bf16x8*)&shBlo[(j * 16 + lm) * 32 + kq];
                #pragma unroll
                for (int i = 0; i < 2; ++i) {
                    acc[i][j] = __builtin_amdgcn_mfma_f32_16x16x32_bf16(alo[i], bhi, acc[i][j], 0, 0, 0);
                    acc[i][j] = __builtin_amdgcn_mfma_f32_16x16x32_bf16(ahi[i], blo, acc[i][j], 0, 0, 0);
                }
            }
        }
    }

    #pragma unroll
    for (int i = 0; i < 2; ++i) {
        #pragma unroll
        for (int j = 0; j < 12; ++j) {
            int col = j * 16 + lm;
            float bias = 0.0f;
            if (fold_bias) bias = (col < 128) ? cvt(b1[col]) : cvt(bsv[col - 128]);
            #pragma unroll
            for (int r = 0; r < 4; ++r) {
                int row = m0 + (2 * w + i) * 16 + (l >> 4) * 4 + r;
                if (row < ND) {
                    float v = acc[i][j][r] + bias;
                    if (col < 128) P1[(size_t)row * 128 + col] = (PT)v;
                    else           P2[(size_t)row * 64 + (col - 128)] = (PT)v;
                }
            }
        }
    }
}

// ---------------------------------------------------------------------------
// Kernel 3: fused edge kernel — VERBATIM R6 (separate shT, no overlay).
// ---------------------------------------------------------------------------
template<typename T, int DTYPE, typename PT>
__global__ __launch_bounds__(256) void edge_mfma2(
        const int* __restrict__ flag,
        const PT* __restrict__ Pd1, const PT* __restrict__ Ps1,
        const PT* __restrict__ Pd2, const PT* __restrict__ Ps2,
        const bf16_t* __restrict__ W2Th, const bf16_t* __restrict__ W2Tl,
        const int* __restrict__ src, const int* __restrict__ dst,
        const T* __restrict__ g1, const T* __restrict__ be1,
        const T* __restrict__ b2, const T* __restrict__ g2,
        const T* __restrict__ be2,
        const T* __restrict__ W3, const T* __restrict__ b3,
        T* __restrict__ out, int E) {
    if (*flag != DTYPE) return;
    __shared__ bf16_t shH[64 * 136];    // h1 hi (pass a) then lo (pass b)
    __shared__ bf16_t shWhi[64 * 136];  // W2^T hi [n][k]
    __shared__ bf16_t shWlo[64 * 136];  // W2^T lo
    __shared__ float  shT[64 * 66];     // t2 fp32

    const int t = threadIdx.x;
    const int w = t >> 6, l = t & 63;
    const int e = t >> 2, q = t & 3;
    const int edge = blockIdx.x * 64 + e;
    const bool valid = edge < E;
    const int ec = valid ? edge : (E - 1);
    const int si = src[ec], di = dst[ec];

    // ---- stage W2T hi/lo ----
    {
        int row = t >> 2, c4 = t & 3;
        const bf16x8* gh = (const bf16x8*)(W2Th + row * 128 + c4 * 32);
        const bf16x8* gl = (const bf16x8*)(W2Tl + row * 128 + c4 * 32);
        bf16x8* dh = (bf16x8*)&shWhi[row * 136 + c4 * 32];
        bf16x8* dl = (bf16x8*)&shWlo[row * 136 + c4 * 32];
        dh[0] = gh[0]; dh[1] = gh[1]; dh[2] = gh[2]; dh[3] = gh[3];
        dl[0] = gl[0]; dl[1] = gl[1]; dl[2] = gl[2]; dl[3] = gl[3];
    }

    // ---- phase 1: fp32 gather + t1 + LN1 + GELU -> shH(hi), hlo in regs ----
    float t1v[32];
    float sum = 0.f, ssq = 0.f;
    #pragma unroll
    for (int j = 0; j < 4; ++j) {
        int ch8 = j * 4 + q;
        float a[8], b[8];
        load8f(Pd1 + (size_t)si * 128 + ch8 * 8, a);
        load8f(Ps1 + (size_t)di * 128 + ch8 * 8, b);
        #pragma unroll
        for (int c = 0; c < 8; ++c) {
            float v = a[c] + b[c];    // b1 folded into Pd1
            t1v[j * 8 + c] = v;
            sum += v; ssq += v * v;
        }
    }
    sum += __shfl_xor(sum, 1); ssq += __shfl_xor(ssq, 1);
    sum += __shfl_xor(sum, 2); ssq += __shfl_xor(ssq, 2);
    float mu   = sum * (1.0f / 128.0f);
    float var  = fmaxf(ssq * (1.0f / 128.0f) - mu * mu, 0.0f);
    float rsig = rsqrtf(var + 1e-5f);

    // identity gather, fp32 exact (bs folded into Pd2)
    float idv[16];
    #pragma unroll
    for (int j = 0; j < 2; ++j) {
        int ch8 = j * 4 + q;
        float a[8], b[8];
        load8f(Pd2 + (size_t)si * 64 + ch8 * 8, a);
        load8f(Ps2 + (size_t)di * 64 + ch8 * 8, b);
        #pragma unroll
        for (int c = 0; c < 8; ++c) idv[j * 8 + c] = a[c] + b[c];
    }

    bf16x8 hlov[4];
    #pragma unroll
    for (int j = 0; j < 4; ++j) {
        int ch8 = j * 4 + q;
        bf16x8 hhi;
        #pragma unroll
        for (int c = 0; c < 8; ++c) {
            int ch = ch8 * 8 + c;
            float h = (t1v[j * 8 + c] - mu) * rsig * cvt(g1[ch]) + cvt(be1[ch]);
            h = gelu_exact(h);
            bf16_t hb = (bf16_t)h;
            hhi[c] = hb;
            hlov[j][c] = (bf16_t)(h - (float)hb);
        }
        *(bf16x8*)&shH[e * 136 + ch8 * 8] = hhi;
    }
    __syncthreads();

    // ---- phase 2, pass a: acc = ahi*bhi + ahi*blo ----
    const int lm = l & 15, kq = (l >> 4) * 8;
    f32x4 acc[4] = {};
    #pragma unroll
    for (int k0 = 0; k0 < 128; k0 += 32) {
        bf16x8 ahi = *(const bf16x8*)&shH[(w * 16 + lm) * 136 + k0 + kq];
        #pragma unroll
        for (int n = 0; n < 4; ++n) {
            bf16x8 bhi = *(const bf16x8*)&shWhi[(n * 16 + lm) * 136 + k0 + kq];
            bf16x8 blo = *(const bf16x8*)&shWlo[(n * 16 + lm) * 136 + k0 + kq];
            acc[n] = __builtin_amdgcn_mfma_f32_16x16x32_bf16(ahi, bhi, acc[n], 0, 0, 0);
            acc[n] = __builtin_amdgcn_mfma_f32_16x16x32_bf16(ahi, blo, acc[n], 0, 0, 0);
        }
    }
    __syncthreads();   // pass-a reads of shH done
    #pragma unroll
    for (int j = 0; j < 4; ++j)
        *(bf16x8*)&shH[e * 136 + (j * 4 + q) * 8] = hlov[j];
    __syncthreads();   // hlo visible
    // ---- phase 2, pass b: acc += alo*bhi ----
    #pragma unroll
    for (int k0 = 0; k0 < 128; k0 += 32) {
        bf16x8 alo = *(const bf16x8*)&shH[(w * 16 + lm) * 136 + k0 + kq];
        #pragma unroll
        for (int n = 0; n < 4; ++n) {
            bf16x8 bhi = *(const bf16x8*)&shWhi[(n * 16 + lm) * 136 + k0 + kq];
            acc[n] = __builtin_amdgcn_mfma_f32_16x16x32_bf16(alo, bhi, acc[n], 0, 0, 0);
        }
    }
    #pragma unroll
    for (int n = 0; n < 4; ++n) {
        int col = n * 16 + lm;
        float b2v = cvt(b2[col]);
        #pragma unroll
        for (int r = 0; r < 4; ++r) {
            int row = w * 16 + (l >> 4) * 4 + r;
            shT[row * 66 + col] = acc[n][r] + b2v;
        }
    }
    __syncthreads();

    // ---- phase 3: LN2 + identity + GELU + W3 dot ----
    float t2v[16];
    float s2 = 0.f, q2 = 0.f;
    #pragma unroll
    for (int j = 0; j < 2; ++j) {
        int base = (j * 4 + q) * 8;
        #pragma unroll
        for (int c = 0; c < 8; ++c) {
            float v = shT[e * 66 + base + c];
            t2v[j * 8 + c] = v;
            s2 += v; q2 += v * v;
        }
    }
    s2 += __shfl_xor(s2, 1); q2 += __shfl_xor(q2, 1);
    s2 += __shfl_xor(s2, 2); q2 += __shfl_xor(q2, 2);
    float mu2  = s2 * (1.0f / 64.0f);
    float var2 = fmaxf(q2 * (1.0f / 64.0f) - mu2 * mu2, 0.0f);
    float rs2  = rsqrtf(var2 + 1e-5f);

    float osum = 0.f;
    #pragma unroll
    for (int j = 0; j < 2; ++j) {
        int base = (j * 4 + q) * 8;
        #pragma unroll
        for (int c = 0; c < 8; ++c) {
            int ch = base + c;
            float v = (t2v[j * 8 + c] - mu2) * rs2 * cvt(g2[ch]) + cvt(be2[ch]);
            v += idv[j * 8 + c];
            v = gelu_exact(v);
            osum += v * cvt(W3[ch]);
        }
    }
    osum += __shfl_xor(osum, 1);
    osum += __shfl_xor(osum, 2);
    if (q == 0 && valid) out[edge] = (T)(osum + cvt(b3[0]));
}

// ---------------------------------------------------------------------------
template<typename PT>
static void launch_all(void* const* d_in, int E, int NDd, int NDs,
                       void* d_out, char* ws, hipStream_t stream) {
    bf16_t* WTdh = (bf16_t*)ws;                     ws += 192 * 256 * 2;
    bf16_t* WTdl = (bf16_t*)ws;                     ws += 192 * 256 * 2;
    bf16_t* WTsh = (bf16_t*)ws;                     ws += 192 * 256 * 2;
    bf16_t* WTsl = (bf16_t*)ws;                     ws += 192 * 256 * 2;
    bf16_t* W2Th = (bf16_t*)ws;                     ws += 64 * 128 * 2;
    bf16_t* W2Tl = (bf16_t*)ws;                     ws += 64 * 128 * 2;
    int*    flag = (int*)ws;                        ws += 256;
    PT* Pd1 = (PT*)ws;                              ws += (size_t)NDd * 128 * sizeof(PT);
    PT* Ps1 = (PT*)ws;                              ws += (size_t)NDs * 128 * sizeof(PT);
    PT* Pd2 = (PT*)ws;                              ws += (size_t)NDd * 64 * sizeof(PT);
    PT* Ps2 = (PT*)ws;

    detect_dtype<<<1, 64, 0, stream>>>((const uint32_t*)d_in[0], flag);

    prep_weights<float, 1><<<224, 256, 0, stream>>>(flag,
        (const float*)d_in[4], (const float*)d_in[14], (const float*)d_in[8],
        WTdh, WTdl, WTsh, WTsl, W2Th, W2Tl);
    prep_weights<bf16_t, 2><<<224, 256, 0, stream>>>(flag,
        (const bf16_t*)d_in[4], (const bf16_t*)d_in[14], (const bf16_t*)d_in[8],
        WTdh, WTdl, WTsh, WTsl, W2Th, W2Tl);

    int gbd = (NDd + 127) / 128, gbs = (NDs + 127) / 128;
    prep_gemm_m<float, 1, PT><<<gbd + gbs, 256, 0, stream>>>(flag,
        (const float*)d_in[0], (const float*)d_in[1],
        WTdh, WTdl, WTsh, WTsl,
        (const float*)d_in[5], (const float*)d_in[15],
        Pd1, Pd2, Ps1, Ps2, NDd, NDs, gbd);
    prep_gemm_m<bf16_t, 2, PT><<<gbd + gbs, 256, 0, stream>>>(flag,
        (const bf16_t*)d_in[0], (const bf16_t*)d_in[1],
        WTdh, WTdl, WTsh, WTsl,
        (const bf16_t*)d_in[5], (const bf16_t*)d_in[15],
        Pd1, Pd2, Ps1, Ps2, NDd, NDs, gbd);

    int geb = (E + 63) / 64;
    edge_mfma2<float, 1, PT><<<geb, 256, 0, stream>>>(flag, Pd1, Ps1, Pd2, Ps2, W2Th, W2Tl,
        (const int*)d_in[2], (const int*)d_in[3],
        (const float*)d_in[6], (const float*)d_in[7], (const float*)d_in[9],
        (const float*)d_in[10], (const float*)d_in[11],
        (const float*)d_in[12], (const float*)d_in[13], (float*)d_out, E);
    edge_mfma2<bf16_t, 2, PT><<<geb, 256, 0, stream>>>(flag, Pd1, Ps1, Pd2, Ps2, W2Th, W2Tl,
        (const int*)d_in[2], (const int*)d_in[3],
        (const bf16_t*)d_in[6], (const bf16_t*)d_in[7], (const bf16_t*)d_in[9],
        (const bf16_t*)d_in[10], (const bf16_t*)d_in[11],
        (const bf16_t*)d_in[12], (const bf16_t*)d_in[13], (bf16_t*)d_out, E);
}

extern "C" void kernel_launch(void* const* d_in, const int* in_sizes, int n_in,
                              void* d_out, int out_size, void* d_ws, size_t ws_size,
                              hipStream_t stream) {
    const int E   = in_sizes[2];
    const int NDd = in_sizes[0] / 256;
    const int NDs = in_sizes[1] / 256;

    size_t fixed = 4 * 192 * 256 * 2 + 2 * 64 * 128 * 2 + 256;
    size_t needF = fixed + (size_t)(NDd + NDs) * 192 * 4;   // fp32 P tables
    if (ws_size >= needF)
        launch_all<float>(d_in, E, NDd, NDs, d_out, (char*)d_ws, stream);
    else
        launch_all<bf16_t>(d_in, E, NDd, NDs, d_out, (char*)d_ws, stream);
}